// Round 8
// baseline (67.932 us; speedup 1.0000x reference)
//
#include <hip/hip_runtime.h>

// out = x @ ((B@A - B0@A0) * s)  ==  ((x@[B|-B0]) @ [A;A0]) * s,  s = 1.
// x[8192][4096] fp32, A/A0[16][4096], B/B0[4096][16].
// Fused row-local kernel: per 16-row tile, GEMM1 (K=4096 via MFMA, split
// across 8 waves, LDS-reduced) then GEMM2 (K=32, one MFMA depth).
// 8 waves/block doubles chip-wide wave count (latency-bound fix, R7).
#define N_TOK 8192
#define D     4096
#define RLO   16
#define R2    32

typedef __bf16  bf16x8  __attribute__((ext_vector_type(8)));
typedef short   short8v __attribute__((ext_vector_type(8)));
typedef float   f32x4   __attribute__((ext_vector_type(4)));

__device__ __forceinline__ short bf1(float f) {
  __bf16 b = (__bf16)f;
  return __builtin_bit_cast(short, b);
}

__device__ __forceinline__ short8v cvt8(float4 lo, float4 hi) {
  bf16x8 b;
  b[0] = (__bf16)lo.x; b[1] = (__bf16)lo.y; b[2] = (__bf16)lo.z; b[3] = (__bf16)lo.w;
  b[4] = (__bf16)hi.x; b[5] = (__bf16)hi.y; b[6] = (__bf16)hi.z; b[7] = (__bf16)hi.w;
  return __builtin_bit_cast(short8v, b);
}

// d_ws layout: PTb [32][4096] bf16 (256 KB) | Qpk [4096][32] bf16 (256 KB)

__global__ __launch_bounds__(256) void prep_kernel(
    const float* __restrict__ A, const float* __restrict__ B,
    const float* __restrict__ A0, const float* __restrict__ B0,
    ushort* __restrict__ PTb, ushort* __restrict__ Qpk) {
  int idx = blockIdx.x * 256 + threadIdx.x;   // 0 .. 32*4096-1
  int r = idx >> 12;
  int k = idx & (D - 1);
  float pt, q;
  if (r < RLO) {
    pt = B[k * RLO + r];
    q  = A[r * D + k];
  } else {
    pt = -B0[k * RLO + (r - RLO)];
    q  = A0[(r - RLO) * D + k];
  }
  PTb[idx] = (ushort)bf1(pt);                 // [r][k], k contiguous
  Qpk[(size_t)k * R2 + r] = (ushort)bf1(q);   // [j][r], r contiguous
}

// Fused: per 16-row tile, 8 waves.
// Phase A: wave w accumulates k in [w*512, w*512+512) via 16 MFMA k-steps;
//   8 wave-partials LDS-reduced; u tile -> bf16 in LDS.
// Phase B: wave w covers j in [w*512, w*512+512): 32 MFMA tiles, nt stores.
__global__ __launch_bounds__(512, 4) void fused_kernel(
    const float* __restrict__ x, const ushort* __restrict__ PTb,
    const ushort* __restrict__ Qpk, float* __restrict__ out) {
  __shared__ float red[8][16][R2 + 2];           // 17.4 KB, padded
  __shared__ __align__(16) ushort usb[16][R2];   // u tile in bf16, 1 KB
  const int tid  = threadIdx.x;
  const int w    = tid >> 6;
  const int lane = tid & 63;
  const int l16  = lane & 15;
  const int kg   = lane >> 4;
  const int row0 = blockIdx.x * 16;
  const int kb   = w * 512 + kg * 8;

  // ---- Phase A: u[row0..row0+15][0..31] ----
  const float*  xp  = x   + (size_t)(row0 + l16) * D + kb;
  const ushort* pb0 = PTb + (size_t)l16 * D + kb;
  const ushort* pb1 = pb0 + (size_t)16 * D;

  f32x4 acc0 = {0.f, 0.f, 0.f, 0.f};
  f32x4 acc1 = {0.f, 0.f, 0.f, 0.f};

#pragma unroll
  for (int s = 0; s < 16; ++s) {
    const int ko = s * 32;
    const float4 alo = *(const float4*)(xp + ko);
    const float4 ahi = *(const float4*)(xp + ko + 4);
    const short8v b0 = *(const short8v*)(pb0 + ko);
    const short8v b1 = *(const short8v*)(pb1 + ko);
    const short8v a  = cvt8(alo, ahi);
    acc0 = __builtin_amdgcn_mfma_f32_16x16x32_bf16(a, b0, acc0, 0, 0, 0);
    acc1 = __builtin_amdgcn_mfma_f32_16x16x32_bf16(a, b1, acc1, 0, 0, 0);
  }

  // D-frag: col = lane&15 (= r), row = (lane>>4)*4 + j (= local x-row)
#pragma unroll
  for (int j = 0; j < 4; ++j) {
    red[w][kg * 4 + j][l16]      = acc0[j];
    red[w][kg * 4 + j][16 + l16] = acc1[j];
  }
  __syncthreads();

  // 512 cells (16 rows x 32 r); 512 threads handle 1 each; sum 8 waves -> bf16
  {
    const int row = tid >> 5;
    const int r   = tid & 31;
    float s = 0.f;
#pragma unroll
    for (int ww = 0; ww < 8; ++ww) s += red[ww][row][r];
    usb[row][r] = (ushort)bf1(s);
  }
  __syncthreads();

  // ---- Phase B: out[row0..row0+15][:] = u_tile @ Q ----
  const short8v ua = *(const short8v*)&usb[l16][kg * 8];
  const f32x4 z = {0.f, 0.f, 0.f, 0.f};
  const int jbase = w * 512;

#pragma unroll 8
  for (int jt = 0; jt < 32; ++jt) {
    const int j = jbase + jt * 16 + l16;
    const short8v qb = *(const short8v*)(Qpk + (size_t)j * R2 + kg * 8);
    const f32x4 d = __builtin_amdgcn_mfma_f32_16x16x32_bf16(ua, qb, z, 0, 0, 0);
    float* o = out + (size_t)(row0 + kg * 4) * D + j;
#pragma unroll
    for (int jr = 0; jr < 4; ++jr)
      __builtin_nontemporal_store(d[jr], o + (size_t)jr * D);
  }
}

extern "C" void kernel_launch(void* const* d_in, const int* in_sizes, int n_in,
                              void* d_out, int out_size, void* d_ws, size_t ws_size,
                              hipStream_t stream) {
  const float* x  = (const float*)d_in[0];
  const float* A  = (const float*)d_in[1];
  const float* B  = (const float*)d_in[2];
  const float* A0 = (const float*)d_in[3];
  const float* B0 = (const float*)d_in[4];
  float* out = (float*)d_out;

  ushort* PTb = (ushort*)d_ws;               // 32*4096 bf16
  ushort* Qpk = PTb + (size_t)R2 * D;        // 4096*32 bf16

  hipLaunchKernelGGL(prep_kernel, dim3((R2 * D) / 256), dim3(256), 0, stream,
                     A, B, A0, B0, PTb, Qpk);
  hipLaunchKernelGGL(fused_kernel, dim3(N_TOK / 16), dim3(512), 0, stream,
                     x, PTb, Qpk, out);
}